// Round 7
// baseline (7122.594 us; speedup 1.0000x reference)
//
#include <hip/hip_runtime.h>

#define NTOKS 3152      // B*T*P = 2*8*197
#define DMODEL 384
#define EDIM 768
#define TWOE 1536
#define SDIM 16
#define RDIM 24
#define XDIM 56         // R + 2S
#define NLAYER 12
#define CLEN 32         // scan chunk length
#define NPATCH 3136     // 16 * 196

typedef __attribute__((ext_vector_type(8))) short bf16x8;
typedef __attribute__((ext_vector_type(4))) float f32x4;

__device__ __forceinline__ float em_silu(float v) { return v / (1.f + __expf(-v)); }

__device__ __forceinline__ unsigned short f2bf(float f) {
  union { float f; unsigned int u; } v; v.f = f;
  const unsigned int r = v.u + 0x7fffu + ((v.u >> 16) & 1u);   // RTNE
  return (unsigned short)(r >> 16);
}
__device__ __forceinline__ unsigned int f2bf2(float lo, float hi) {
  return (unsigned int)f2bf(lo) | ((unsigned int)f2bf(hi) << 16);
}
__device__ __forceinline__ float bfbits_lo(unsigned int u) {
  union { unsigned int u; float f; } v; v.u = u << 16; return v.f;
}
__device__ __forceinline__ float bfbits_hi(unsigned int u) {
  union { unsigned int u; float f; } v; v.u = u & 0xffff0000u; return v.f;
}
__device__ __forceinline__ unsigned int addbf2(unsigned int a, unsigned int b) {
  return f2bf2(bfbits_lo(a) + bfbits_lo(b), bfbits_hi(a) + bfbits_hi(b));
}
__device__ __forceinline__ uint4 addbf8(uint4 a, uint4 b) {
  uint4 r;
  r.x = addbf2(a.x, b.x); r.y = addbf2(a.y, b.y);
  r.z = addbf2(a.z, b.z); r.w = addbf2(a.w, b.w);
  return r;
}
__device__ __forceinline__ float em_softplus(float a) {
  return (a > 20.f) ? a : log1pf(__expf(a));
}

// ---------------- im2col (bf16 out) for patch embed: col[3136][768] ----------------
__global__ __launch_bounds__(256)
void em_im2col(const float* __restrict__ x, unsigned short* __restrict__ col) {
  const int g = blockIdx.x * 256 + threadIdx.x;   // pr*768 + cc
  const int pr = g / 768;
  const int cc = g - pr * 768;
  const int np = pr % 196;
  const int bt = pr / 196;
  const int t = bt & 7, b = bt >> 3;
  const int hp = np / 14, wp = np - hp * 14;
  const int c = cc >> 8;
  const int rem = cc & 255;
  const int ph = rem >> 4, pw = rem & 15;
  col[g] = f2bf(x[(((size_t)(b * 3 + c) * 8 + t) * 224 + (hp * 16 + ph)) * 224 + (wp * 16 + pw)]);
}

// -------- patch embed epilogue fused with first residual+RMSNorm --------
// v = emb(tok,d); residual = v; xn_bf = rmsnorm(v) * norm0_w
__global__ __launch_bounds__(DMODEL)
void em_embed_norm(const float* __restrict__ tmpP, const float* __restrict__ pb,
                   const float* __restrict__ cls, const float* __restrict__ pos,
                   const float* __restrict__ w,
                   float* __restrict__ residual, unsigned short* __restrict__ xn_bf) {
  const int tok = blockIdx.x;
  const int d = threadIdx.x;
  const int p = tok % 197;
  const int bt = tok / 197;
  const int t = bt & 7;
  float v;
  if (p == 0) {
    v = cls[d] + pos[d];
  } else {
    const int np = p - 1;
    const float div = powf(10000.f, (float)(d & ~1) * (1.f / 384.f));
    const float ang = (float)t / div;
    const float enc = (d & 1) ? cosf(ang) : sinf(ang);
    v = tmpP[((size_t)bt * 196 + np) * DMODEL + d] + pb[d] + pos[(size_t)p * DMODEL + d] + enc;
  }
  const size_t idx = (size_t)tok * DMODEL + d;
  residual[idx] = v;
  float ss = v * v;
  #pragma unroll
  for (int off = 32; off; off >>= 1) ss += __shfl_xor(ss, off, 64);
  __shared__ float red[6];
  if ((d & 63) == 0) red[d >> 6] = ss;
  __syncthreads();
  float tot = 0.f;
  #pragma unroll
  for (int i = 0; i < 6; ++i) tot += red[i];
  const float scale = rsqrtf(tot * (1.f / 384.f) + 1e-5f);
  xn_bf[idx] = f2bf(v * scale * w[d]);
}

// ================ MFMA GEMM, bf16 A in memory, fp32 W: C = A @ W^T ================
#define TM 128
#define TN 64
#define LDT 40   // ushorts per LDS row (32 + 8 pad)
__global__ __launch_bounds__(256)
void em_gemm_abf(const unsigned short* __restrict__ A,
                 const float* __restrict__ W, float* __restrict__ C,
                 int M, int N, int K) {
  __shared__ unsigned short As[TM * LDT];
  __shared__ unsigned short Bs[TN * LDT];
  const int tid = threadIdx.x;
  const int bm = blockIdx.y * TM;
  const int bn = blockIdx.x * TN;
  const int wave = tid >> 6, lane = tid & 63;
  const int wm = (wave >> 1) * 64, wn = (wave & 1) * 32;
  const int mq = lane & 15, quad = lane >> 4;
  f32x4 acc[4][2] = {};
  const int ar = tid >> 1;
  const int ah = (tid & 1) * 16;
  const int br = tid >> 2;
  const int bk = (tid & 3) * 8;

  for (int kk = 0; kk < K; kk += 32) {
    {
      uint4 v0 = {0, 0, 0, 0}, v1 = {0, 0, 0, 0};
      const int row = bm + ar;
      if (row < M) {
        const uint4* pa = reinterpret_cast<const uint4*>(A + (size_t)row * K + kk + ah);
        v0 = pa[0]; v1 = pa[1];
      }
      uint4* dst = reinterpret_cast<uint4*>(As + ar * LDT + ah);
      dst[0] = v0; dst[1] = v1;
    }
    {
      const float* p = W + (size_t)(bn + br) * K + kk + bk;
      const float4 v0 = *reinterpret_cast<const float4*>(p);
      const float4 v1 = *reinterpret_cast<const float4*>(p + 4);
      uint4 pk;
      pk.x = f2bf2(v0.x, v0.y); pk.y = f2bf2(v0.z, v0.w);
      pk.z = f2bf2(v1.x, v1.y); pk.w = f2bf2(v1.z, v1.w);
      *reinterpret_cast<uint4*>(Bs + br * LDT + bk) = pk;
    }
    __syncthreads();
    bf16x8 bfr[2];
    #pragma unroll
    for (int j = 0; j < 2; ++j)
      bfr[j] = *reinterpret_cast<const bf16x8*>(Bs + (wn + j * 16 + mq) * LDT + quad * 8);
    #pragma unroll
    for (int i = 0; i < 4; ++i) {
      const bf16x8 afr = *reinterpret_cast<const bf16x8*>(As + (wm + i * 16 + mq) * LDT + quad * 8);
      acc[i][0] = __builtin_amdgcn_mfma_f32_16x16x32_bf16(afr, bfr[0], acc[i][0], 0, 0, 0);
      acc[i][1] = __builtin_amdgcn_mfma_f32_16x16x32_bf16(afr, bfr[1], acc[i][1], 0, 0, 0);
    }
    __syncthreads();
  }
  #pragma unroll
  for (int i = 0; i < 4; ++i) {
    const int mbase = bm + wm + i * 16 + quad * 4;
    #pragma unroll
    for (int j = 0; j < 2; ++j) {
      const int col = bn + wn + j * 16 + mq;
      #pragma unroll
      for (int p = 0; p < 4; ++p) {
        const int m = mbase + p;
        if (m < M) C[(size_t)m * N + col] = acc[i][j][p];
      }
    }
  }
}

// ===== fused outproj GEMM + residual add + RMSNorm (or final norm) =====
// C[32,384] tile per block; epilogue: v = C + res, res = v, out = rmsnorm(v)*w
// A bf16 (yb_f [+yb_r]); W fp32 (384 x 768). Grid: ceil(M/32) blocks.
__global__ __launch_bounds__(256)
void em_outproj_fused(const unsigned short* __restrict__ A, const unsigned short* __restrict__ A2,
                      const float* __restrict__ W,
                      float* __restrict__ res, const float* __restrict__ norm_w,
                      unsigned short* __restrict__ xn_out, float* __restrict__ final_out,
                      int M) {
  __shared__ __align__(16) char smem[50688];
  unsigned short* As = (unsigned short*)smem;               // 32*LDT shorts
  unsigned short* Bs = As + 32 * LDT;                       // 384*LDT shorts
  float* vsm = (float*)smem;                                // [32][388] (repurposed)
  float* red = (float*)(smem + 49664);                      // [32][8]
  const int tid = threadIdx.x;
  const int bm = blockIdx.x * 32;
  const int wave = tid >> 6, lane = tid & 63;
  const int wc = wave * 96;
  const int mq = lane & 15, quad = lane >> 4;
  f32x4 acc[2][6] = {};

  for (int kk = 0; kk < EDIM; kk += 32) {
    if (tid < 128) {                       // A: 32 rows x 32 shorts
      const int r = tid >> 2, q = (tid & 3) * 8;
      uint4 v = {0, 0, 0, 0};
      const int row = bm + r;
      if (row < M) {
        v = *reinterpret_cast<const uint4*>(A + (size_t)row * EDIM + kk + q);
        if (A2) {
          const uint4 v2 = *reinterpret_cast<const uint4*>(A2 + (size_t)row * EDIM + kk + q);
          v = addbf8(v, v2);
        }
      }
      *reinterpret_cast<uint4*>(As + r * LDT + q) = v;
    }
    #pragma unroll
    for (int t = 0; t < 6; ++t) {          // B: 384 rows x 32 floats -> bf16
      const int idx = tid + t * 256;
      const int r = idx >> 2, q = (idx & 3) * 8;
      const float* p = W + (size_t)r * EDIM + kk + q;
      const float4 v0 = *reinterpret_cast<const float4*>(p);
      const float4 v1 = *reinterpret_cast<const float4*>(p + 4);
      uint4 pk;
      pk.x = f2bf2(v0.x, v0.y); pk.y = f2bf2(v0.z, v0.w);
      pk.z = f2bf2(v1.x, v1.y); pk.w = f2bf2(v1.z, v1.w);
      *reinterpret_cast<uint4*>(Bs + r * LDT + q) = pk;
    }
    __syncthreads();
    bf16x8 afr[2];
    #pragma unroll
    for (int i = 0; i < 2; ++i)
      afr[i] = *reinterpret_cast<const bf16x8*>(As + (i * 16 + mq) * LDT + quad * 8);
    #pragma unroll
    for (int j = 0; j < 6; ++j) {
      const bf16x8 bfr = *reinterpret_cast<const bf16x8*>(Bs + (wc + j * 16 + mq) * LDT + quad * 8);
      acc[0][j] = __builtin_amdgcn_mfma_f32_16x16x32_bf16(afr[0], bfr, acc[0][j], 0, 0, 0);
      acc[1][j] = __builtin_amdgcn_mfma_f32_16x16x32_bf16(afr[1], bfr, acc[1][j], 0, 0, 0);
    }
    __syncthreads();
  }
  // spill accumulators to LDS (repurposes staging buffers)
  #pragma unroll
  for (int i = 0; i < 2; ++i) {
    #pragma unroll
    for (int j = 0; j < 6; ++j) {
      #pragma unroll
      for (int p = 0; p < 4; ++p)
        vsm[(i * 16 + quad * 4 + p) * 388 + wc + j * 16 + mq] = acc[i][j][p];
    }
  }
  __syncthreads();
  // residual add + row sum-of-squares: 8 threads per row, 48 cols each
  const int r = tid >> 3, seg = tid & 7;
  const int row = bm + r;
  float ss = 0.f;
  for (int k = 0; k < 48; ++k) {
    const int c = seg * 48 + k;
    float v = vsm[r * 388 + c];
    if (row < M) v += res[(size_t)row * DMODEL + c];
    vsm[r * 388 + c] = v;
    ss += v * v;
  }
  red[r * 8 + seg] = ss;
  __syncthreads();
  float tot = 0.f;
  #pragma unroll
  for (int t = 0; t < 8; ++t) tot += red[r * 8 + t];
  const float scale = rsqrtf(tot * (1.f / 384.f) + 1e-5f);
  if (row < M) {
    for (int k = 0; k < 48; ++k) {
      const int c = seg * 48 + k;
      const float v = vsm[r * 388 + c];
      res[(size_t)row * DMODEL + c] = v;
      const float o = v * scale * norm_w[c];
      if (xn_out) xn_out[(size_t)row * DMODEL + c] = f2bf(o);
      else final_out[(size_t)row * DMODEL + c] = o;
    }
  }
}

// ================ transposed xproj GEMM: dblT[64, NTOKS] = xp[56,768] @ u^T ======
__global__ __launch_bounds__(256)
void em_gemm_xpT(const unsigned short* __restrict__ ubf, const unsigned short* __restrict__ ubr,
                 const float* __restrict__ xpf, const float* __restrict__ xpr,
                 float* __restrict__ dblTf, float* __restrict__ dblTr) {
  const int dir = blockIdx.z;
  const unsigned short* U = dir ? ubr : ubf;
  const float* W = dir ? xpr : xpf;
  float* C = dir ? dblTr : dblTf;
  __shared__ unsigned short As[64 * LDT];   // xp tile (56 real rows)
  __shared__ unsigned short Bs[64 * LDT];   // u tile (64 tokens)
  const int tid = threadIdx.x;
  const int bn = blockIdx.x * 64;           // token base
  const int wave = tid >> 6, lane = tid & 63;
  const int wm = wave * 16;
  const int mq = lane & 15, quad = lane >> 4;
  f32x4 acc[4] = {};
  const int sr = tid >> 2;
  const int sq = (tid & 3) * 8;

  for (int kk = 0; kk < EDIM; kk += 32) {
    {
      uint4 pk = {0, 0, 0, 0};
      if (sr < XDIM) {
        const float* p = W + (size_t)sr * EDIM + kk + sq;
        const float4 v0 = *reinterpret_cast<const float4*>(p);
        const float4 v1 = *reinterpret_cast<const float4*>(p + 4);
        pk.x = f2bf2(v0.x, v0.y); pk.y = f2bf2(v0.z, v0.w);
        pk.z = f2bf2(v1.x, v1.y); pk.w = f2bf2(v1.z, v1.w);
      }
      *reinterpret_cast<uint4*>(As + sr * LDT + sq) = pk;
    }
    {
      uint4 v = {0, 0, 0, 0};
      const int tok = bn + sr;
      if (tok < NTOKS)
        v = *reinterpret_cast<const uint4*>(U + (size_t)tok * EDIM + kk + sq);
      *reinterpret_cast<uint4*>(Bs + sr * LDT + sq) = v;
    }
    __syncthreads();
    const bf16x8 afr = *reinterpret_cast<const bf16x8*>(As + (wm + mq) * LDT + quad * 8);
    #pragma unroll
    for (int j = 0; j < 4; ++j) {
      const bf16x8 bfr = *reinterpret_cast<const bf16x8*>(Bs + (j * 16 + mq) * LDT + quad * 8);
      acc[j] = __builtin_amdgcn_mfma_f32_16x16x32_bf16(afr, bfr, acc[j], 0, 0, 0);
    }
    __syncthreads();
  }
  #pragma unroll
  for (int j = 0; j < 4; ++j) {
    const int tok = bn + j * 16 + mq;
    if (tok < NTOKS) {
      #pragma unroll
      for (int p = 0; p < 4; ++p) {
        const int m = wm + quad * 4 + p;
        C[(size_t)m * NTOKS + tok] = acc[j][p];
      }
    }
  }
}

// ---------------- depthwise conv + SiLU; writes u fp32 (scan) and bf16 (xp GEMM) ----------------
__global__ __launch_bounds__(256)
void em_conv_silu(const float* __restrict__ xz,
                  const float* __restrict__ cwf, const float* __restrict__ cbf,
                  const float* __restrict__ cwr, const float* __restrict__ cbr,
                  float* __restrict__ uf, float* __restrict__ ur,
                  unsigned short* __restrict__ ubf, unsigned short* __restrict__ ubr, int L) {
  const int e = blockIdx.x * 256 + threadIdx.x;
  const int tok = blockIdx.y;
  const int dir = blockIdx.z;
  const int l = tok % L;
  const float* cw = dir ? cwr : cwf;
  const float* cb = dir ? cbr : cbf;
  const float w0 = cw[e * 4 + 0], w1 = cw[e * 4 + 1], w2 = cw[e * 4 + 2], w3 = cw[e * 4 + 3];
  float acc = cb[e];
  const float* base = xz + (size_t)tok * TWOE + e;
  if (dir == 0) {
    acc += base[0] * w3;
    if (l >= 1) acc += base[-(ptrdiff_t)TWOE] * w2;
    if (l >= 2) acc += base[-(ptrdiff_t)(2 * TWOE)] * w1;
    if (l >= 3) acc += base[-(ptrdiff_t)(3 * TWOE)] * w0;
  } else {
    acc += base[0] * w3;
    if (l + 1 < L) acc += base[TWOE] * w2;
    if (l + 2 < L) acc += base[2 * TWOE] * w1;
    if (l + 3 < L) acc += base[3 * TWOE] * w0;
  }
  const float v = em_silu(acc);
  const size_t idx = (size_t)tok * EDIM + e;
  (dir ? ur : uf)[idx] = v;
  (dir ? ubr : ubf)[idx] = f2bf(v);
}

// ================= chunked scan, dt-projection fused (CLEN=32) =================
__global__ __launch_bounds__(256)
void em_scan_sum(const float* __restrict__ uf, const float* __restrict__ ur,
                 const float* __restrict__ dblTf, const float* __restrict__ dblTr,
                 const float* __restrict__ dtwf, const float* __restrict__ dtwr,
                 const float* __restrict__ dtbf, const float* __restrict__ dtbr,
                 const float* __restrict__ Alogf, const float* __restrict__ Alogr,
                 float* __restrict__ Pfw, float* __restrict__ Prv,
                 float* __restrict__ Hfw, float* __restrict__ Hrv,
                 int L, int nchunks) {
  const int dir = blockIdx.z;
  const int n = blockIdx.y / nchunks;
  const int c = blockIdx.y % nchunks;
  const int tid = threadIdx.x;
  const int e = blockIdx.x * 256 + tid;
  const float* u = dir ? ur : uf;
  const float* dblT = dir ? dblTr : dblTf;
  const float* dtw = dir ? dtwr : dtwf;
  const float* dtb = dir ? dtbr : dtbf;
  const float* Alog = dir ? Alogr : Alogf;
  float* P = dir ? Prv : Pfw;
  float* H = dir ? Hrv : Hfw;
  const int p0 = c * CLEN;
  const int len = min(CLEN, L - p0);
  __shared__ float Bs[CLEN][SDIM];
  __shared__ float dtl[CLEN][RDIM];
  for (int i = tid; i < CLEN * (SDIM + RDIM); i += 256) {
    const int r = i >> 5;              // 0..39
    const int j = i & (CLEN - 1);
    if (j < len) {
      const int pos = p0 + j;
      const int l = dir ? (L - 1 - pos) : pos;
      const int src = (r < SDIM) ? (RDIM + r) : (r - SDIM);
      const float val = dblT[(size_t)src * NTOKS + (size_t)n * L + l];
      if (r < SDIM) Bs[j][r] = val; else dtl[j][r - SDIM] = val;
    }
  }
  __syncthreads();
  float dw[RDIM];
  #pragma unroll
  for (int j = 0; j < RDIM; ++j) dw[j] = dtw[(size_t)e * RDIM + j];
  const float bias = dtb[e];
  float A[SDIM], h[SDIM], Pp[SDIM];
  #pragma unroll
  for (int s = 0; s < SDIM; ++s) {
    A[s] = -__expf(Alog[e * SDIM + s]);
    h[s] = 0.f; Pp[s] = 1.f;
  }
  for (int j = 0; j < len; ++j) {
    const int pos = p0 + j;
    const int l = dir ? (L - 1 - pos) : pos;
    const size_t tok = (size_t)n * L + l;
    float a0 = bias;
    #pragma unroll
    for (int rr = 0; rr < RDIM; ++rr) a0 += dtl[j][rr] * dw[rr];
    const float dtv = em_softplus(a0);
    const float dtu = dtv * u[tok * EDIM + e];
    #pragma unroll
    for (int s = 0; s < SDIM; ++s) {
      const float a = __expf(dtv * A[s]);
      h[s] = a * h[s] + dtu * Bs[j][s];
      Pp[s] *= a;
    }
  }
  const size_t base = ((size_t)(n * nchunks + c) * EDIM + e) * SDIM;
  #pragma unroll
  for (int s = 0; s < SDIM; ++s) { P[base + s] = Pp[s]; H[base + s] = h[s]; }
}

__global__ __launch_bounds__(256)
void em_scan_combine(const float* __restrict__ Pfw, const float* __restrict__ Prv,
                     float* __restrict__ Hfw, float* __restrict__ Hrv, int nchunks) {
  const int dir = blockIdx.z;
  const int idx = blockIdx.x * 256 + threadIdx.x;
  const int n = idx / (EDIM * SDIM);
  const int r = idx % (EDIM * SDIM);
  const float* P = dir ? Prv : Pfw;
  float* H = dir ? Hrv : Hfw;
  float h = 0.f;
  for (int c = 0; c < nchunks; ++c) {
    const size_t b = (size_t)(n * nchunks + c) * (EDIM * SDIM) + r;
    const float pv = P[b];
    const float hf = H[b];
    H[b] = h;
    h = pv * h + hf;
  }
}

__global__ __launch_bounds__(256)
void em_scan_out(const float* __restrict__ uf, const float* __restrict__ ur,
                 const float* __restrict__ dblTf, const float* __restrict__ dblTr,
                 const float* __restrict__ dtwf, const float* __restrict__ dtwr,
                 const float* __restrict__ dtbf, const float* __restrict__ dtbr,
                 const float* __restrict__ xz,
                 const float* __restrict__ Alogf, const float* __restrict__ Alogr,
                 const float* __restrict__ Dpf, const float* __restrict__ Dpr,
                 const float* __restrict__ Hfw, const float* __restrict__ Hrv,
                 unsigned short* __restrict__ ybf, unsigned short* __restrict__ ybr,
                 int L, int nchunks) {
  const int dir = blockIdx.z;
  const int n = blockIdx.y / nchunks;
  const int c = blockIdx.y % nchunks;
  const int tid = threadIdx.x;
  const int e = blockIdx.x * 256 + tid;
  const float* u = dir ? ur : uf;
  const float* dblT = dir ? dblTr : dblTf;
  const float* dtw = dir ? dtwr : dtwf;
  const float* dtb = dir ? dtbr : dtbf;
  const float* Alog = dir ? Alogr : Alogf;
  const float* Dp = dir ? Dpr : Dpf;
  const float* Hin = dir ? Hrv : Hfw;
  unsigned short* y = dir ? ybr : ybf;
  const int p0 = c * CLEN;
  const int len = min(CLEN, L - p0);
  __shared__ float Bs[CLEN][SDIM];
  __shared__ float Cs[CLEN][SDIM];
  __shared__ float dtl[CLEN][RDIM];
  for (int i = tid; i < CLEN * (2 * SDIM + RDIM); i += 256) {
    const int r = i >> 5;              // 0..55
    const int j = i & (CLEN - 1);
    if (j < len) {
      const int pos = p0 + j;
      const int l = dir ? (L - 1 - pos) : pos;
      const int src = (r < 2 * SDIM) ? (RDIM + r) : (r - 2 * SDIM);
      const float val = dblT[(size_t)src * NTOKS + (size_t)n * L + l];
      if (r < SDIM) Bs[j][r] = val;
      else if (r < 2 * SDIM) Cs[j][r - SDIM] = val;
      else dtl[j][r - 2 * SDIM] = val;
    }
  }
  __syncthreads();
  float dw[RDIM];
  #pragma unroll
  for (int j = 0; j < RDIM; ++j) dw[j] = dtw[(size_t)e * RDIM + j];
  const float bias = dtb[e];
  float A[SDIM], h[SDIM];
  const size_t base = ((size_t)(n * nchunks + c) * EDIM + e) * SDIM;
  #pragma unroll
  for (int s = 0; s < SDIM; ++s) {
    A[s] = -__expf(Alog[e * SDIM + s]);
    h[s] = Hin[base + s];
  }
  const float De = Dp[e];
  for (int j = 0; j < len; ++j) {
    const int pos = p0 + j;
    const int l = dir ? (L - 1 - pos) : pos;
    const size_t tok = (size_t)n * L + l;
    float a0 = bias;
    #pragma unroll
    for (int rr = 0; rr < RDIM; ++rr) a0 += dtl[j][rr] * dw[rr];
    const float dtv = em_softplus(a0);
    const float uv = u[tok * EDIM + e];
    const float dtu = dtv * uv;
    float acc = 0.f;
    #pragma unroll
    for (int s = 0; s < SDIM; ++s) {
      const float a = __expf(dtv * A[s]);
      h[s] = a * h[s] + dtu * Bs[j][s];
      acc += h[s] * Cs[j][s];
    }
    const float z = xz[tok * TWOE + EDIM + e];
    y[tok * EDIM + e] = f2bf((acc + uv * De) * em_silu(z));
  }
}

extern "C" void kernel_launch(void* const* d_in, const int* in_sizes, int n_in,
                              void* d_out, int out_size, void* d_ws, size_t ws_size,
                              hipStream_t stream) {
  const float* x         = (const float*)d_in[0];
  const float* patch_w   = (const float*)d_in[1];
  const float* patch_b   = (const float*)d_in[2];
  const float* cls_tok   = (const float*)d_in[3];
  const float* pos_emb   = (const float*)d_in[4];
  const float* normf     = (const float*)d_in[5];
  const float* sp_conv_w   = (const float*)d_in[6];
  const float* sp_conv_b   = (const float*)d_in[7];
  const float* sp_xproj    = (const float*)d_in[8];
  const float* sp_dtw      = (const float*)d_in[9];
  const float* sp_dtb      = (const float*)d_in[10];
  const float* sp_Alog     = (const float*)d_in[11];
  const float* sp_D        = (const float*)d_in[12];
  const float* sp_conv_w_r = (const float*)d_in[13];
  const float* sp_conv_b_r = (const float*)d_in[14];
  const float* sp_xproj_r  = (const float*)d_in[15];
  const float* sp_dtw_r    = (const float*)d_in[16];
  const float* sp_dtb_r    = (const float*)d_in[17];
  const float* sp_Alog_r   = (const float*)d_in[18];
  const float* sp_D_r      = (const float*)d_in[19];
  const float* tm_conv_w   = (const float*)d_in[20];
  const float* tm_conv_b   = (const float*)d_in[21];
  const float* tm_xproj    = (const float*)d_in[22];
  const float* tm_dtw      = (const float*)d_in[23];
  const float* tm_dtb      = (const float*)d_in[24];
  const float* tm_Alog     = (const float*)d_in[25];
  const float* tm_D        = (const float*)d_in[26];
  const float* sp_norm     = (const float*)d_in[27];
  const float* sp_inproj   = (const float*)d_in[28];
  const float* sp_outproj  = (const float*)d_in[29];
  const float* tm_norm     = (const float*)d_in[30];
  const float* tm_inproj   = (const float*)d_in[31];
  const float* tm_outproj  = (const float*)d_in[32];

  float* ws = (float*)d_ws;
  size_t o = 0;
  float* residual = ws + o; o += (size_t)NTOKS * DMODEL;
  float* xz       = ws + o; o += (size_t)NTOKS * TWOE;
  float* u_f      = ws + o; o += (size_t)NTOKS * EDIM;
  float* u_r      = ws + o; o += (size_t)NTOKS * EDIM;
  float* dblT_f   = ws + o; o += (size_t)64 * NTOKS;
  float* dblT_r   = ws + o; o += (size_t)64 * NTOKS;
  unsigned short* xn_bf = (unsigned short*)(ws + o); o += (size_t)NTOKS * DMODEL / 2;
  unsigned short* ub_f  = (unsigned short*)(ws + o); o += (size_t)NTOKS * EDIM;      // 2 dirs
  unsigned short* ub_r  = ub_f + (size_t)NTOKS * EDIM;
  unsigned short* yb_f  = (unsigned short*)(ws + o); o += (size_t)NTOKS * EDIM;      // 2 dirs
  unsigned short* yb_r  = yb_f + (size_t)NTOKS * EDIM;
  const size_t sum_elems = (size_t)112 * EDIM * SDIM;
  float* scanP_f  = ws + o; o += sum_elems;
  float* scanP_r  = ws + o; o += sum_elems;
  float* scanH_f  = ws + o; o += sum_elems;
  float* scanH_r  = ws + o; o += sum_elems;

  unsigned short* im2col_bf = ub_f;            // aliases: unused until first conv
  float* patch_tmp = u_f;

  const int L_sp = 197, NC_sp = (L_sp + CLEN - 1) / CLEN;   // 7
  const int L_tm = 1576, NC_tm = (L_tm + CLEN - 1) / CLEN;  // 50
  const int MT = (NTOKS + TM - 1) / TM;                     // 25
  const int NT64 = (NTOKS + 63) / 64;                       // 50
  const int MO = (NTOKS + 31) / 32;                         // 99

  // -------- patch embed: im2col(bf16) + MFMA GEMM + fused epilogue/norm --------
  em_im2col<<<(NPATCH * 768) / 256, 256, 0, stream>>>(x, im2col_bf);
  em_gemm_abf<<<dim3(DMODEL / TN, (NPATCH + TM - 1) / TM), 256, 0, stream>>>(
      im2col_bf, patch_w, patch_tmp, NPATCH, DMODEL, 768);
  em_embed_norm<<<NTOKS, DMODEL, 0, stream>>>(patch_tmp, patch_b, cls_tok, pos_emb,
                                              sp_norm, residual, xn_bf);

  // -------- 12 spatial bimamba blocks: N=16 sequences of L=197 --------
  for (int i = 0; i < NLAYER; ++i) {
    em_gemm_abf<<<dim3(TWOE / TN, MT), 256, 0, stream>>>(
        xn_bf, sp_inproj + (size_t)i * TWOE * DMODEL, xz, NTOKS, TWOE, DMODEL);
    em_conv_silu<<<dim3(EDIM / 256, NTOKS, 2), 256, 0, stream>>>(
        xz, sp_conv_w + (size_t)i * EDIM * 4, sp_conv_b + (size_t)i * EDIM,
        sp_conv_w_r + (size_t)i * EDIM * 4, sp_conv_b_r + (size_t)i * EDIM,
        u_f, u_r, ub_f, ub_r, L_sp);
    em_gemm_xpT<<<dim3(NT64, 1, 2), 256, 0, stream>>>(
        ub_f, ub_r, sp_xproj + (size_t)i * XDIM * EDIM, sp_xproj_r + (size_t)i * XDIM * EDIM,
        dblT_f, dblT_r);
    em_scan_sum<<<dim3(EDIM / 256, 16 * NC_sp, 2), 256, 0, stream>>>(
        u_f, u_r, dblT_f, dblT_r,
        sp_dtw + (size_t)i * EDIM * RDIM, sp_dtw_r + (size_t)i * EDIM * RDIM,
        sp_dtb + (size_t)i * EDIM, sp_dtb_r + (size_t)i * EDIM,
        sp_Alog + (size_t)i * EDIM * SDIM, sp_Alog_r + (size_t)i * EDIM * SDIM,
        scanP_f, scanP_r, scanH_f, scanH_r, L_sp, NC_sp);
    em_scan_combine<<<dim3(16 * EDIM * SDIM / 256, 1, 2), 256, 0, stream>>>(
        scanP_f, scanP_r, scanH_f, scanH_r, NC_sp);
    em_scan_out<<<dim3(EDIM / 256, 16 * NC_sp, 2), 256, 0, stream>>>(
        u_f, u_r, dblT_f, dblT_r,
        sp_dtw + (size_t)i * EDIM * RDIM, sp_dtw_r + (size_t)i * EDIM * RDIM,
        sp_dtb + (size_t)i * EDIM, sp_dtb_r + (size_t)i * EDIM, xz,
        sp_Alog + (size_t)i * EDIM * SDIM, sp_Alog_r + (size_t)i * EDIM * SDIM,
        sp_D + (size_t)i * EDIM, sp_D_r + (size_t)i * EDIM,
        scanH_f, scanH_r, yb_f, yb_r, L_sp, NC_sp);
    const float* next_w = (i < NLAYER - 1) ? sp_norm + (size_t)(i + 1) * DMODEL : tm_norm;
    em_outproj_fused<<<MO, 256, 0, stream>>>(
        yb_f, yb_r, sp_outproj + (size_t)i * DMODEL * EDIM,
        residual, next_w, xn_bf, nullptr, NTOKS);
  }

  // -------- 12 temporal mamba blocks: N=2 sequences of L=1576 --------
  for (int i = 0; i < NLAYER; ++i) {
    em_gemm_abf<<<dim3(TWOE / TN, MT), 256, 0, stream>>>(
        xn_bf, tm_inproj + (size_t)i * TWOE * DMODEL, xz, NTOKS, TWOE, DMODEL);
    em_conv_silu<<<dim3(EDIM / 256, NTOKS, 1), 256, 0, stream>>>(
        xz, tm_conv_w + (size_t)i * EDIM * 4, tm_conv_b + (size_t)i * EDIM,
        tm_conv_w + (size_t)i * EDIM * 4, tm_conv_b + (size_t)i * EDIM,
        u_f, u_r, ub_f, ub_r, L_tm);
    em_gemm_xpT<<<dim3(NT64, 1, 1), 256, 0, stream>>>(
        ub_f, ub_r, tm_xproj + (size_t)i * XDIM * EDIM, tm_xproj + (size_t)i * XDIM * EDIM,
        dblT_f, dblT_r);
    em_scan_sum<<<dim3(EDIM / 256, 2 * NC_tm, 1), 256, 0, stream>>>(
        u_f, u_r, dblT_f, dblT_r,
        tm_dtw + (size_t)i * EDIM * RDIM, tm_dtw + (size_t)i * EDIM * RDIM,
        tm_dtb + (size_t)i * EDIM, tm_dtb + (size_t)i * EDIM,
        tm_Alog + (size_t)i * EDIM * SDIM, tm_Alog + (size_t)i * EDIM * SDIM,
        scanP_f, scanP_r, scanH_f, scanH_r, L_tm, NC_tm);
    em_scan_combine<<<dim3(2 * EDIM * SDIM / 256, 1, 1), 256, 0, stream>>>(
        scanP_f, scanP_r, scanH_f, scanH_r, NC_tm);
    em_scan_out<<<dim3(EDIM / 256, 2 * NC_tm, 1), 256, 0, stream>>>(
        u_f, u_r, dblT_f, dblT_r,
        tm_dtw + (size_t)i * EDIM * RDIM, tm_dtw + (size_t)i * EDIM * RDIM,
        tm_dtb + (size_t)i * EDIM, tm_dtb + (size_t)i * EDIM, xz,
        tm_Alog + (size_t)i * EDIM * SDIM, tm_Alog + (size_t)i * EDIM * SDIM,
        tm_D + (size_t)i * EDIM, tm_D + (size_t)i * EDIM,
        scanH_f, scanH_r, yb_f, yb_r, L_tm, NC_tm);
    const bool last = (i == NLAYER - 1);
    const float* next_w = last ? normf : tm_norm + (size_t)(i + 1) * DMODEL;
    em_outproj_fused<<<MO, 256, 0, stream>>>(
        yb_f, nullptr, tm_outproj + (size_t)i * DMODEL * EDIM,
        residual, next_w, last ? nullptr : xn_bf, last ? (float*)d_out : nullptr, NTOKS);
  }
}

// Round 8
// 5196.555 us; speedup vs baseline: 1.3706x; 1.3706x over previous
//
#include <hip/hip_runtime.h>

#define NTOKS 3152      // B*T*P = 2*8*197
#define DMODEL 384
#define EDIM 768
#define TWOE 1536
#define SDIM 16
#define RDIM 24
#define XDIM 56         // R + 2S
#define NLAYER 12
#define CLEN 32         // scan chunk length
#define NPATCH 3136     // 16 * 196

typedef __attribute__((ext_vector_type(8))) short bf16x8;
typedef __attribute__((ext_vector_type(4))) float f32x4;

__device__ __forceinline__ float em_silu(float v) { return v / (1.f + __expf(-v)); }

__device__ __forceinline__ unsigned short f2bf(float f) {
  union { float f; unsigned int u; } v; v.f = f;
  const unsigned int r = v.u + 0x7fffu + ((v.u >> 16) & 1u);   // RTNE
  return (unsigned short)(r >> 16);
}
__device__ __forceinline__ unsigned int f2bf2(float lo, float hi) {
  return (unsigned int)f2bf(lo) | ((unsigned int)f2bf(hi) << 16);
}
__device__ __forceinline__ float bfbits_lo(unsigned int u) {
  union { unsigned int u; float f; } v; v.u = u << 16; return v.f;
}
__device__ __forceinline__ float bfbits_hi(unsigned int u) {
  union { unsigned int u; float f; } v; v.u = u & 0xffff0000u; return v.f;
}
__device__ __forceinline__ unsigned int addbf2(unsigned int a, unsigned int b) {
  return f2bf2(bfbits_lo(a) + bfbits_lo(b), bfbits_hi(a) + bfbits_hi(b));
}
__device__ __forceinline__ uint4 addbf8(uint4 a, uint4 b) {
  uint4 r;
  r.x = addbf2(a.x, b.x); r.y = addbf2(a.y, b.y);
  r.z = addbf2(a.z, b.z); r.w = addbf2(a.w, b.w);
  return r;
}
__device__ __forceinline__ float em_softplus(float a) {
  return (a > 20.f) ? a : log1pf(__expf(a));
}

// ---------------- im2col (bf16 out) for patch embed: col[3136][768] ----------------
__global__ __launch_bounds__(256)
void em_im2col(const float* __restrict__ x, unsigned short* __restrict__ col) {
  const int g = blockIdx.x * 256 + threadIdx.x;   // pr*768 + cc
  const int pr = g / 768;
  const int cc = g - pr * 768;
  const int np = pr % 196;
  const int bt = pr / 196;
  const int t = bt & 7, b = bt >> 3;
  const int hp = np / 14, wp = np - hp * 14;
  const int c = cc >> 8;
  const int rem = cc & 255;
  const int ph = rem >> 4, pw = rem & 15;
  col[g] = f2bf(x[(((size_t)(b * 3 + c) * 8 + t) * 224 + (hp * 16 + ph)) * 224 + (wp * 16 + pw)]);
}

// -------- patch embed epilogue fused with first residual+RMSNorm --------
__global__ __launch_bounds__(DMODEL)
void em_embed_norm(const float* __restrict__ tmpP, const float* __restrict__ pb,
                   const float* __restrict__ cls, const float* __restrict__ pos,
                   const float* __restrict__ w,
                   float* __restrict__ residual, unsigned short* __restrict__ xn_bf) {
  const int tok = blockIdx.x;
  const int d = threadIdx.x;
  const int p = tok % 197;
  const int bt = tok / 197;
  const int t = bt & 7;
  float v;
  if (p == 0) {
    v = cls[d] + pos[d];
  } else {
    const int np = p - 1;
    const float div = powf(10000.f, (float)(d & ~1) * (1.f / 384.f));
    const float ang = (float)t / div;
    const float enc = (d & 1) ? cosf(ang) : sinf(ang);
    v = tmpP[((size_t)bt * 196 + np) * DMODEL + d] + pb[d] + pos[(size_t)p * DMODEL + d] + enc;
  }
  const size_t idx = (size_t)tok * DMODEL + d;
  residual[idx] = v;
  float ss = v * v;
  #pragma unroll
  for (int off = 32; off; off >>= 1) ss += __shfl_xor(ss, off, 64);
  __shared__ float red[6];
  if ((d & 63) == 0) red[d >> 6] = ss;
  __syncthreads();
  float tot = 0.f;
  #pragma unroll
  for (int i = 0; i < 6; ++i) tot += red[i];
  const float scale = rsqrtf(tot * (1.f / 384.f) + 1e-5f);
  xn_bf[idx] = f2bf(v * scale * w[d]);
}

// ---------------- residual add + RMSNorm; writes bf16 (layers) or fp32 (final) ----------------
__global__ __launch_bounds__(DMODEL)
void em_add_rmsnorm(const float* __restrict__ hidden, const float* __restrict__ res_in,
                    float* __restrict__ res_out, const float* __restrict__ w,
                    float* __restrict__ out, unsigned short* __restrict__ out_bf) {
  const int tok = blockIdx.x;
  const int d = threadIdx.x;
  const size_t idx = (size_t)tok * DMODEL + d;
  const float v = hidden[idx] + res_in[idx];
  if (res_out) res_out[idx] = v;
  float ss = v * v;
  #pragma unroll
  for (int off = 32; off; off >>= 1) ss += __shfl_xor(ss, off, 64);
  __shared__ float red[6];
  if ((d & 63) == 0) red[d >> 6] = ss;
  __syncthreads();
  float tot = 0.f;
  #pragma unroll
  for (int i = 0; i < 6; ++i) tot += red[i];
  const float scale = rsqrtf(tot * (1.f / 384.f) + 1e-5f);
  const float r = v * scale * w[d];
  if (out_bf) out_bf[idx] = f2bf(r);
  else out[idx] = r;
}

// ================ MFMA GEMM, bf16 A (+A2) in memory, fp32 W: C = (A+A2) @ W^T ================
#define TM 128
#define TN 64
#define LDT 40   // ushorts per LDS row (32 + 8 pad)
__global__ __launch_bounds__(256)
void em_gemm_abf(const unsigned short* __restrict__ A, const unsigned short* __restrict__ A2,
                 const float* __restrict__ W, float* __restrict__ C,
                 int M, int N, int K) {
  __shared__ unsigned short As[TM * LDT];
  __shared__ unsigned short Bs[TN * LDT];
  const int tid = threadIdx.x;
  const int bm = blockIdx.y * TM;
  const int bn = blockIdx.x * TN;
  const int wave = tid >> 6, lane = tid & 63;
  const int wm = (wave >> 1) * 64, wn = (wave & 1) * 32;
  const int mq = lane & 15, quad = lane >> 4;
  f32x4 acc[4][2] = {};
  const int ar = tid >> 1;
  const int ah = (tid & 1) * 16;
  const int br = tid >> 2;
  const int bk = (tid & 3) * 8;

  for (int kk = 0; kk < K; kk += 32) {
    {
      uint4 v0 = {0, 0, 0, 0}, v1 = {0, 0, 0, 0};
      const int row = bm + ar;
      if (row < M) {
        const uint4* pa = reinterpret_cast<const uint4*>(A + (size_t)row * K + kk + ah);
        v0 = pa[0]; v1 = pa[1];
        if (A2) {
          const uint4* pb = reinterpret_cast<const uint4*>(A2 + (size_t)row * K + kk + ah);
          v0 = addbf8(v0, pb[0]); v1 = addbf8(v1, pb[1]);
        }
      }
      uint4* dst = reinterpret_cast<uint4*>(As + ar * LDT + ah);
      dst[0] = v0; dst[1] = v1;
    }
    {
      const float* p = W + (size_t)(bn + br) * K + kk + bk;
      const float4 v0 = *reinterpret_cast<const float4*>(p);
      const float4 v1 = *reinterpret_cast<const float4*>(p + 4);
      uint4 pk;
      pk.x = f2bf2(v0.x, v0.y); pk.y = f2bf2(v0.z, v0.w);
      pk.z = f2bf2(v1.x, v1.y); pk.w = f2bf2(v1.z, v1.w);
      *reinterpret_cast<uint4*>(Bs + br * LDT + bk) = pk;
    }
    __syncthreads();
    bf16x8 bfr[2];
    #pragma unroll
    for (int j = 0; j < 2; ++j)
      bfr[j] = *reinterpret_cast<const bf16x8*>(Bs + (wn + j * 16 + mq) * LDT + quad * 8);
    #pragma unroll
    for (int i = 0; i < 4; ++i) {
      const bf16x8 afr = *reinterpret_cast<const bf16x8*>(As + (wm + i * 16 + mq) * LDT + quad * 8);
      acc[i][0] = __builtin_amdgcn_mfma_f32_16x16x32_bf16(afr, bfr[0], acc[i][0], 0, 0, 0);
      acc[i][1] = __builtin_amdgcn_mfma_f32_16x16x32_bf16(afr, bfr[1], acc[i][1], 0, 0, 0);
    }
    __syncthreads();
  }
  #pragma unroll
  for (int i = 0; i < 4; ++i) {
    const int mbase = bm + wm + i * 16 + quad * 4;
    #pragma unroll
    for (int j = 0; j < 2; ++j) {
      const int col = bn + wn + j * 16 + mq;
      #pragma unroll
      for (int p = 0; p < 4; ++p) {
        const int m = mbase + p;
        if (m < M) C[(size_t)m * N + col] = acc[i][j][p];
      }
    }
  }
}

// ================ transposed xproj GEMM: dblT[64, NTOKS] = xp[56,768] @ u^T ======
__global__ __launch_bounds__(256)
void em_gemm_xpT(const unsigned short* __restrict__ ubf, const unsigned short* __restrict__ ubr,
                 const float* __restrict__ xpf, const float* __restrict__ xpr,
                 float* __restrict__ dblTf, float* __restrict__ dblTr) {
  const int dir = blockIdx.z;
  const unsigned short* U = dir ? ubr : ubf;
  const float* W = dir ? xpr : xpf;
  float* C = dir ? dblTr : dblTf;
  __shared__ unsigned short As[64 * LDT];   // xp tile (56 real rows)
  __shared__ unsigned short Bs[64 * LDT];   // u tile (64 tokens)
  const int tid = threadIdx.x;
  const int bn = blockIdx.x * 64;           // token base
  const int wave = tid >> 6, lane = tid & 63;
  const int wm = wave * 16;
  const int mq = lane & 15, quad = lane >> 4;
  f32x4 acc[4] = {};
  const int sr = tid >> 2;
  const int sq = (tid & 3) * 8;

  for (int kk = 0; kk < EDIM; kk += 32) {
    {
      uint4 pk = {0, 0, 0, 0};
      if (sr < XDIM) {
        const float* p = W + (size_t)sr * EDIM + kk + sq;
        const float4 v0 = *reinterpret_cast<const float4*>(p);
        const float4 v1 = *reinterpret_cast<const float4*>(p + 4);
        pk.x = f2bf2(v0.x, v0.y); pk.y = f2bf2(v0.z, v0.w);
        pk.z = f2bf2(v1.x, v1.y); pk.w = f2bf2(v1.z, v1.w);
      }
      *reinterpret_cast<uint4*>(As + sr * LDT + sq) = pk;
    }
    {
      uint4 v = {0, 0, 0, 0};
      const int tok = bn + sr;
      if (tok < NTOKS)
        v = *reinterpret_cast<const uint4*>(U + (size_t)tok * EDIM + kk + sq);
      *reinterpret_cast<uint4*>(Bs + sr * LDT + sq) = v;
    }
    __syncthreads();
    const bf16x8 afr = *reinterpret_cast<const bf16x8*>(As + (wm + mq) * LDT + quad * 8);
    #pragma unroll
    for (int j = 0; j < 4; ++j) {
      const bf16x8 bfr = *reinterpret_cast<const bf16x8*>(Bs + (j * 16 + mq) * LDT + quad * 8);
      acc[j] = __builtin_amdgcn_mfma_f32_16x16x32_bf16(afr, bfr, acc[j], 0, 0, 0);
    }
    __syncthreads();
  }
  #pragma unroll
  for (int j = 0; j < 4; ++j) {
    const int tok = bn + j * 16 + mq;
    if (tok < NTOKS) {
      #pragma unroll
      for (int p = 0; p < 4; ++p) {
        const int m = wm + quad * 4 + p;
        C[(size_t)m * NTOKS + tok] = acc[j][p];
      }
    }
  }
}

// ---------------- depthwise conv + SiLU; writes u fp32 (scan) and bf16 (xp GEMM) ----------------
__global__ __launch_bounds__(256)
void em_conv_silu(const float* __restrict__ xz,
                  const float* __restrict__ cwf, const float* __restrict__ cbf,
                  const float* __restrict__ cwr, const float* __restrict__ cbr,
                  float* __restrict__ uf, float* __restrict__ ur,
                  unsigned short* __restrict__ ubf, unsigned short* __restrict__ ubr, int L) {
  const int e = blockIdx.x * 256 + threadIdx.x;
  const int tok = blockIdx.y;
  const int dir = blockIdx.z;
  const int l = tok % L;
  const float* cw = dir ? cwr : cwf;
  const float* cb = dir ? cbr : cbf;
  const float w0 = cw[e * 4 + 0], w1 = cw[e * 4 + 1], w2 = cw[e * 4 + 2], w3 = cw[e * 4 + 3];
  float acc = cb[e];
  const float* base = xz + (size_t)tok * TWOE + e;
  if (dir == 0) {
    acc += base[0] * w3;
    if (l >= 1) acc += base[-(ptrdiff_t)TWOE] * w2;
    if (l >= 2) acc += base[-(ptrdiff_t)(2 * TWOE)] * w1;
    if (l >= 3) acc += base[-(ptrdiff_t)(3 * TWOE)] * w0;
  } else {
    acc += base[0] * w3;
    if (l + 1 < L) acc += base[TWOE] * w2;
    if (l + 2 < L) acc += base[2 * TWOE] * w1;
    if (l + 3 < L) acc += base[3 * TWOE] * w0;
  }
  const float v = em_silu(acc);
  const size_t idx = (size_t)tok * EDIM + e;
  (dir ? ur : uf)[idx] = v;
  (dir ? ubr : ubf)[idx] = f2bf(v);
}

// ================= chunked scan, dt-projection fused (CLEN=32) =================
__global__ __launch_bounds__(256)
void em_scan_sum(const float* __restrict__ uf, const float* __restrict__ ur,
                 const float* __restrict__ dblTf, const float* __restrict__ dblTr,
                 const float* __restrict__ dtwf, const float* __restrict__ dtwr,
                 const float* __restrict__ dtbf, const float* __restrict__ dtbr,
                 const float* __restrict__ Alogf, const float* __restrict__ Alogr,
                 float* __restrict__ Pfw, float* __restrict__ Prv,
                 float* __restrict__ Hfw, float* __restrict__ Hrv,
                 int L, int nchunks) {
  const int dir = blockIdx.z;
  const int n = blockIdx.y / nchunks;
  const int c = blockIdx.y % nchunks;
  const int tid = threadIdx.x;
  const int e = blockIdx.x * 256 + tid;
  const float* u = dir ? ur : uf;
  const float* dblT = dir ? dblTr : dblTf;
  const float* dtw = dir ? dtwr : dtwf;
  const float* dtb = dir ? dtbr : dtbf;
  const float* Alog = dir ? Alogr : Alogf;
  float* P = dir ? Prv : Pfw;
  float* H = dir ? Hrv : Hfw;
  const int p0 = c * CLEN;
  const int len = min(CLEN, L - p0);
  __shared__ float Bs[CLEN][SDIM];
  __shared__ float dtl[CLEN][RDIM];
  for (int i = tid; i < CLEN * (SDIM + RDIM); i += 256) {
    const int r = i >> 5;              // 0..39
    const int j = i & (CLEN - 1);
    if (j < len) {
      const int pos = p0 + j;
      const int l = dir ? (L - 1 - pos) : pos;
      const int src = (r < SDIM) ? (RDIM + r) : (r - SDIM);
      const float val = dblT[(size_t)src * NTOKS + (size_t)n * L + l];
      if (r < SDIM) Bs[j][r] = val; else dtl[j][r - SDIM] = val;
    }
  }
  __syncthreads();
  float dw[RDIM];
  #pragma unroll
  for (int j = 0; j < RDIM; ++j) dw[j] = dtw[(size_t)e * RDIM + j];
  const float bias = dtb[e];
  float A[SDIM], h[SDIM], Pp[SDIM];
  #pragma unroll
  for (int s = 0; s < SDIM; ++s) {
    A[s] = -__expf(Alog[e * SDIM + s]);
    h[s] = 0.f; Pp[s] = 1.f;
  }
  for (int j = 0; j < len; ++j) {
    const int pos = p0 + j;
    const int l = dir ? (L - 1 - pos) : pos;
    const size_t tok = (size_t)n * L + l;
    float a0 = bias;
    #pragma unroll
    for (int rr = 0; rr < RDIM; ++rr) a0 += dtl[j][rr] * dw[rr];
    const float dtv = em_softplus(a0);
    const float dtu = dtv * u[tok * EDIM + e];
    #pragma unroll
    for (int s = 0; s < SDIM; ++s) {
      const float a = __expf(dtv * A[s]);
      h[s] = a * h[s] + dtu * Bs[j][s];
      Pp[s] *= a;
    }
  }
  const size_t base = ((size_t)(n * nchunks + c) * EDIM + e) * SDIM;
  #pragma unroll
  for (int s = 0; s < SDIM; ++s) { P[base + s] = Pp[s]; H[base + s] = h[s]; }
}

__global__ __launch_bounds__(256)
void em_scan_combine(const float* __restrict__ Pfw, const float* __restrict__ Prv,
                     float* __restrict__ Hfw, float* __restrict__ Hrv, int nchunks) {
  const int dir = blockIdx.z;
  const int idx = blockIdx.x * 256 + threadIdx.x;
  const int n = idx / (EDIM * SDIM);
  const int r = idx % (EDIM * SDIM);
  const float* P = dir ? Prv : Pfw;
  float* H = dir ? Hrv : Hfw;
  float h = 0.f;
  for (int c = 0; c < nchunks; ++c) {
    const size_t b = (size_t)(n * nchunks + c) * (EDIM * SDIM) + r;
    const float pv = P[b];
    const float hf = H[b];
    H[b] = h;
    h = pv * h + hf;
  }
}

__global__ __launch_bounds__(256)
void em_scan_out(const float* __restrict__ uf, const float* __restrict__ ur,
                 const float* __restrict__ dblTf, const float* __restrict__ dblTr,
                 const float* __restrict__ dtwf, const float* __restrict__ dtwr,
                 const float* __restrict__ dtbf, const float* __restrict__ dtbr,
                 const float* __restrict__ xz,
                 const float* __restrict__ Alogf, const float* __restrict__ Alogr,
                 const float* __restrict__ Dpf, const float* __restrict__ Dpr,
                 const float* __restrict__ Hfw, const float* __restrict__ Hrv,
                 unsigned short* __restrict__ ybf, unsigned short* __restrict__ ybr,
                 int L, int nchunks) {
  const int dir = blockIdx.z;
  const int n = blockIdx.y / nchunks;
  const int c = blockIdx.y % nchunks;
  const int tid = threadIdx.x;
  const int e = blockIdx.x * 256 + tid;
  const float* u = dir ? ur : uf;
  const float* dblT = dir ? dblTr : dblTf;
  const float* dtw = dir ? dtwr : dtwf;
  const float* dtb = dir ? dtbr : dtbf;
  const float* Alog = dir ? Alogr : Alogf;
  const float* Dp = dir ? Dpr : Dpf;
  const float* Hin = dir ? Hrv : Hfw;
  unsigned short* y = dir ? ybr : ybf;
  const int p0 = c * CLEN;
  const int len = min(CLEN, L - p0);
  __shared__ float Bs[CLEN][SDIM];
  __shared__ float Cs[CLEN][SDIM];
  __shared__ float dtl[CLEN][RDIM];
  for (int i = tid; i < CLEN * (2 * SDIM + RDIM); i += 256) {
    const int r = i >> 5;              // 0..55
    const int j = i & (CLEN - 1);
    if (j < len) {
      const int pos = p0 + j;
      const int l = dir ? (L - 1 - pos) : pos;
      const int src = (r < 2 * SDIM) ? (RDIM + r) : (r - 2 * SDIM);
      const float val = dblT[(size_t)src * NTOKS + (size_t)n * L + l];
      if (r < SDIM) Bs[j][r] = val;
      else if (r < 2 * SDIM) Cs[j][r - SDIM] = val;
      else dtl[j][r - 2 * SDIM] = val;
    }
  }
  __syncthreads();
  float dw[RDIM];
  #pragma unroll
  for (int j = 0; j < RDIM; ++j) dw[j] = dtw[(size_t)e * RDIM + j];
  const float bias = dtb[e];
  float A[SDIM], h[SDIM];
  const size_t base = ((size_t)(n * nchunks + c) * EDIM + e) * SDIM;
  #pragma unroll
  for (int s = 0; s < SDIM; ++s) {
    A[s] = -__expf(Alog[e * SDIM + s]);
    h[s] = Hin[base + s];
  }
  const float De = Dp[e];
  for (int j = 0; j < len; ++j) {
    const int pos = p0 + j;
    const int l = dir ? (L - 1 - pos) : pos;
    const size_t tok = (size_t)n * L + l;
    float a0 = bias;
    #pragma unroll
    for (int rr = 0; rr < RDIM; ++rr) a0 += dtl[j][rr] * dw[rr];
    const float dtv = em_softplus(a0);
    const float uv = u[tok * EDIM + e];
    const float dtu = dtv * uv;
    float acc = 0.f;
    #pragma unroll
    for (int s = 0; s < SDIM; ++s) {
      const float a = __expf(dtv * A[s]);
      h[s] = a * h[s] + dtu * Bs[j][s];
      acc += h[s] * Cs[j][s];
    }
    const float z = xz[tok * TWOE + EDIM + e];
    y[tok * EDIM + e] = f2bf((acc + uv * De) * em_silu(z));
  }
}

extern "C" void kernel_launch(void* const* d_in, const int* in_sizes, int n_in,
                              void* d_out, int out_size, void* d_ws, size_t ws_size,
                              hipStream_t stream) {
  const float* x         = (const float*)d_in[0];
  const float* patch_w   = (const float*)d_in[1];
  const float* patch_b   = (const float*)d_in[2];
  const float* cls_tok   = (const float*)d_in[3];
  const float* pos_emb   = (const float*)d_in[4];
  const float* normf     = (const float*)d_in[5];
  const float* sp_conv_w   = (const float*)d_in[6];
  const float* sp_conv_b   = (const float*)d_in[7];
  const float* sp_xproj    = (const float*)d_in[8];
  const float* sp_dtw      = (const float*)d_in[9];
  const float* sp_dtb      = (const float*)d_in[10];
  const float* sp_Alog     = (const float*)d_in[11];
  const float* sp_D        = (const float*)d_in[12];
  const float* sp_conv_w_r = (const float*)d_in[13];
  const float* sp_conv_b_r = (const float*)d_in[14];
  const float* sp_xproj_r  = (const float*)d_in[15];
  const float* sp_dtw_r    = (const float*)d_in[16];
  const float* sp_dtb_r    = (const float*)d_in[17];
  const float* sp_Alog_r   = (const float*)d_in[18];
  const float* sp_D_r      = (const float*)d_in[19];
  const float* tm_conv_w   = (const float*)d_in[20];
  const float* tm_conv_b   = (const float*)d_in[21];
  const float* tm_xproj    = (const float*)d_in[22];
  const float* tm_dtw      = (const float*)d_in[23];
  const float* tm_dtb      = (const float*)d_in[24];
  const float* tm_Alog     = (const float*)d_in[25];
  const float* tm_D        = (const float*)d_in[26];
  const float* sp_norm     = (const float*)d_in[27];
  const float* sp_inproj   = (const float*)d_in[28];
  const float* sp_outproj  = (const float*)d_in[29];
  const float* tm_norm     = (const float*)d_in[30];
  const float* tm_inproj   = (const float*)d_in[31];
  const float* tm_outproj  = (const float*)d_in[32];

  float* ws = (float*)d_ws;
  size_t o = 0;
  float* hidden   = ws + o; o += (size_t)NTOKS * DMODEL;
  float* residual = ws + o; o += (size_t)NTOKS * DMODEL;
  float* xz       = ws + o; o += (size_t)NTOKS * TWOE;
  float* u_f      = ws + o; o += (size_t)NTOKS * EDIM;
  float* u_r      = ws + o; o += (size_t)NTOKS * EDIM;
  float* dblT_f   = ws + o; o += (size_t)64 * NTOKS;
  float* dblT_r   = ws + o; o += (size_t)64 * NTOKS;
  unsigned short* xn_bf = (unsigned short*)(ws + o); o += (size_t)NTOKS * DMODEL / 2;
  unsigned short* ub_f  = (unsigned short*)(ws + o); o += (size_t)NTOKS * EDIM;      // 2 dirs
  unsigned short* ub_r  = ub_f + (size_t)NTOKS * EDIM;
  unsigned short* yb_f  = (unsigned short*)(ws + o); o += (size_t)NTOKS * EDIM;      // 2 dirs
  unsigned short* yb_r  = yb_f + (size_t)NTOKS * EDIM;
  const size_t sum_elems = (size_t)112 * EDIM * SDIM;
  float* scanP_f  = ws + o; o += sum_elems;
  float* scanP_r  = ws + o; o += sum_elems;
  float* scanH_f  = ws + o; o += sum_elems;
  float* scanH_r  = ws + o; o += sum_elems;

  unsigned short* im2col_bf = ub_f;            // aliases: unused until first conv
  float* patch_tmp = u_f;

  const int L_sp = 197, NC_sp = (L_sp + CLEN - 1) / CLEN;   // 7
  const int L_tm = 1576, NC_tm = (L_tm + CLEN - 1) / CLEN;  // 50
  const int MT = (NTOKS + TM - 1) / TM;                     // 25
  const int NT64 = (NTOKS + 63) / 64;                       // 50

  // -------- patch embed: im2col(bf16) + MFMA GEMM + fused epilogue/norm --------
  em_im2col<<<(NPATCH * 768) / 256, 256, 0, stream>>>(x, im2col_bf);
  em_gemm_abf<<<dim3(DMODEL / TN, (NPATCH + TM - 1) / TM), 256, 0, stream>>>(
      im2col_bf, nullptr, patch_w, patch_tmp, NPATCH, DMODEL, 768);
  em_embed_norm<<<NTOKS, DMODEL, 0, stream>>>(patch_tmp, patch_b, cls_tok, pos_emb,
                                              sp_norm, residual, xn_bf);

  // -------- 12 spatial bimamba blocks: N=16 sequences of L=197 --------
  for (int i = 0; i < NLAYER; ++i) {
    em_gemm_abf<<<dim3(TWOE / TN, MT), 256, 0, stream>>>(
        xn_bf, nullptr, sp_inproj + (size_t)i * TWOE * DMODEL, xz, NTOKS, TWOE, DMODEL);
    em_conv_silu<<<dim3(EDIM / 256, NTOKS, 2), 256, 0, stream>>>(
        xz, sp_conv_w + (size_t)i * EDIM * 4, sp_conv_b + (size_t)i * EDIM,
        sp_conv_w_r + (size_t)i * EDIM * 4, sp_conv_b_r + (size_t)i * EDIM,
        u_f, u_r, ub_f, ub_r, L_sp);
    em_gemm_xpT<<<dim3(NT64, 1, 2), 256, 0, stream>>>(
        ub_f, ub_r, sp_xproj + (size_t)i * XDIM * EDIM, sp_xproj_r + (size_t)i * XDIM * EDIM,
        dblT_f, dblT_r);
    em_scan_sum<<<dim3(EDIM / 256, 16 * NC_sp, 2), 256, 0, stream>>>(
        u_f, u_r, dblT_f, dblT_r,
        sp_dtw + (size_t)i * EDIM * RDIM, sp_dtw_r + (size_t)i * EDIM * RDIM,
        sp_dtb + (size_t)i * EDIM, sp_dtb_r + (size_t)i * EDIM,
        sp_Alog + (size_t)i * EDIM * SDIM, sp_Alog_r + (size_t)i * EDIM * SDIM,
        scanP_f, scanP_r, scanH_f, scanH_r, L_sp, NC_sp);
    em_scan_combine<<<dim3(16 * EDIM * SDIM / 256, 1, 2), 256, 0, stream>>>(
        scanP_f, scanP_r, scanH_f, scanH_r, NC_sp);
    em_scan_out<<<dim3(EDIM / 256, 16 * NC_sp, 2), 256, 0, stream>>>(
        u_f, u_r, dblT_f, dblT_r,
        sp_dtw + (size_t)i * EDIM * RDIM, sp_dtw_r + (size_t)i * EDIM * RDIM,
        sp_dtb + (size_t)i * EDIM, sp_dtb_r + (size_t)i * EDIM, xz,
        sp_Alog + (size_t)i * EDIM * SDIM, sp_Alog_r + (size_t)i * EDIM * SDIM,
        sp_D + (size_t)i * EDIM, sp_D_r + (size_t)i * EDIM,
        scanH_f, scanH_r, yb_f, yb_r, L_sp, NC_sp);
    em_gemm_abf<<<dim3(DMODEL / TN, MT), 256, 0, stream>>>(
        yb_f, yb_r, sp_outproj + (size_t)i * DMODEL * EDIM, hidden, NTOKS, DMODEL, EDIM);
    const float* next_w = (i < NLAYER - 1) ? sp_norm + (size_t)(i + 1) * DMODEL : tm_norm;
    em_add_rmsnorm<<<NTOKS, DMODEL, 0, stream>>>(hidden, residual, residual,
                                                 next_w, nullptr, xn_bf);
  }

  // -------- 12 temporal mamba blocks: N=2 sequences of L=1576 --------
  for (int i = 0; i < NLAYER; ++i) {
    em_gemm_abf<<<dim3(TWOE / TN, MT), 256, 0, stream>>>(
        xn_bf, nullptr, tm_inproj + (size_t)i * TWOE * DMODEL, xz, NTOKS, TWOE, DMODEL);
    em_conv_silu<<<dim3(EDIM / 256, NTOKS, 1), 256, 0, stream>>>(
        xz, tm_conv_w + (size_t)i * EDIM * 4, tm_conv_b + (size_t)i * EDIM,
        tm_conv_w + (size_t)i * EDIM * 4, tm_conv_b + (size_t)i * EDIM,
        u_f, u_r, ub_f, ub_r, L_tm);
    em_gemm_xpT<<<dim3(NT64, 1, 1), 256, 0, stream>>>(
        ub_f, ub_r, tm_xproj + (size_t)i * XDIM * EDIM, tm_xproj + (size_t)i * XDIM * EDIM,
        dblT_f, dblT_r);
    em_scan_sum<<<dim3(EDIM / 256, 2 * NC_tm, 1), 256, 0, stream>>>(
        u_f, u_r, dblT_f, dblT_r,
        tm_dtw + (size_t)i * EDIM * RDIM, tm_dtw + (size_t)i * EDIM * RDIM,
        tm_dtb + (size_t)i * EDIM, tm_dtb + (size_t)i * EDIM,
        tm_Alog + (size_t)i * EDIM * SDIM, tm_Alog + (size_t)i * EDIM * SDIM,
        scanP_f, scanP_r, scanH_f, scanH_r, L_tm, NC_tm);
    em_scan_combine<<<dim3(2 * EDIM * SDIM / 256, 1, 1), 256, 0, stream>>>(
        scanP_f, scanP_r, scanH_f, scanH_r, NC_tm);
    em_scan_out<<<dim3(EDIM / 256, 2 * NC_tm, 1), 256, 0, stream>>>(
        u_f, u_r, dblT_f, dblT_r,
        tm_dtw + (size_t)i * EDIM * RDIM, tm_dtw + (size_t)i * EDIM * RDIM,
        tm_dtb + (size_t)i * EDIM, tm_dtb + (size_t)i * EDIM, xz,
        tm_Alog + (size_t)i * EDIM * SDIM, tm_Alog + (size_t)i * EDIM * SDIM,
        tm_D + (size_t)i * EDIM, tm_D + (size_t)i * EDIM,
        scanH_f, scanH_r, yb_f, yb_r, L_tm, NC_tm);
    em_gemm_abf<<<dim3(DMODEL / TN, MT), 256, 0, stream>>>(
        yb_f, nullptr, tm_outproj + (size_t)i * DMODEL * EDIM, hidden, NTOKS, DMODEL, EDIM);
    const bool last = (i == NLAYER - 1);
    const float* next_w = last ? normf : tm_norm + (size_t)(i + 1) * DMODEL;
    em_add_rmsnorm<<<NTOKS, DMODEL, 0, stream>>>(hidden, residual, last ? nullptr : residual,
                                                 next_w, last ? (float*)d_out : nullptr,
                                                 last ? nullptr : xn_bf);
  }
}

// Round 9
// 4501.550 us; speedup vs baseline: 1.5823x; 1.1544x over previous
//
#include <hip/hip_runtime.h>

#define NTOKS 3152      // B*T*P = 2*8*197
#define DMODEL 384
#define EDIM 768
#define TWOE 1536
#define SDIM 16
#define RDIM 24
#define XDIM 56         // R + 2S
#define NLAYER 12
#define NPATCH 3136     // 16 * 196

typedef __attribute__((ext_vector_type(8))) short bf16x8;
typedef __attribute__((ext_vector_type(4))) float f32x4;

__device__ __forceinline__ float em_silu(float v) { return v / (1.f + __expf(-v)); }

__device__ __forceinline__ unsigned short f2bf(float f) {
  union { float f; unsigned int u; } v; v.f = f;
  const unsigned int r = v.u + 0x7fffu + ((v.u >> 16) & 1u);   // RTNE
  return (unsigned short)(r >> 16);
}
__device__ __forceinline__ unsigned int f2bf2(float lo, float hi) {
  return (unsigned int)f2bf(lo) | ((unsigned int)f2bf(hi) << 16);
}
__device__ __forceinline__ float bf2f(unsigned short s) {
  union { unsigned int u; float f; } v; v.u = (unsigned int)s << 16; return v.f;
}
__device__ __forceinline__ float bfbits_lo(unsigned int u) {
  union { unsigned int u; float f; } v; v.u = u << 16; return v.f;
}
__device__ __forceinline__ float bfbits_hi(unsigned int u) {
  union { unsigned int u; float f; } v; v.u = u & 0xffff0000u; return v.f;
}
__device__ __forceinline__ unsigned int addbf2(unsigned int a, unsigned int b) {
  return f2bf2(bfbits_lo(a) + bfbits_lo(b), bfbits_hi(a) + bfbits_hi(b));
}
__device__ __forceinline__ uint4 addbf8(uint4 a, uint4 b) {
  uint4 r;
  r.x = addbf2(a.x, b.x); r.y = addbf2(a.y, b.y);
  r.z = addbf2(a.z, b.z); r.w = addbf2(a.w, b.w);
  return r;
}
__device__ __forceinline__ float em_softplus(float a) {
  return (a > 20.f) ? a : log1pf(__expf(a));
}

// ---------------- im2col (bf16 out) for patch embed: col[3136][768] ----------------
__global__ __launch_bounds__(256)
void em_im2col(const float* __restrict__ x, unsigned short* __restrict__ col) {
  const int g = blockIdx.x * 256 + threadIdx.x;   // pr*768 + cc
  const int pr = g / 768;
  const int cc = g - pr * 768;
  const int np = pr % 196;
  const int bt = pr / 196;
  const int t = bt & 7, b = bt >> 3;
  const int hp = np / 14, wp = np - hp * 14;
  const int c = cc >> 8;
  const int rem = cc & 255;
  const int ph = rem >> 4, pw = rem & 15;
  col[g] = f2bf(x[(((size_t)(b * 3 + c) * 8 + t) * 224 + (hp * 16 + ph)) * 224 + (wp * 16 + pw)]);
}

// -------- patch embed epilogue fused with first residual+RMSNorm --------
__global__ __launch_bounds__(DMODEL)
void em_embed_norm(const float* __restrict__ tmpP, const float* __restrict__ pb,
                   const float* __restrict__ cls, const float* __restrict__ pos,
                   const float* __restrict__ w,
                   float* __restrict__ residual, unsigned short* __restrict__ xn_bf) {
  const int tok = blockIdx.x;
  const int d = threadIdx.x;
  const int p = tok % 197;
  const int bt = tok / 197;
  const int t = bt & 7;
  float v;
  if (p == 0) {
    v = cls[d] + pos[d];
  } else {
    const int np = p - 1;
    const float div = powf(10000.f, (float)(d & ~1) * (1.f / 384.f));
    const float ang = (float)t / div;
    const float enc = (d & 1) ? cosf(ang) : sinf(ang);
    v = tmpP[((size_t)bt * 196 + np) * DMODEL + d] + pb[d] + pos[(size_t)p * DMODEL + d] + enc;
  }
  const size_t idx = (size_t)tok * DMODEL + d;
  residual[idx] = v;
  float ss = v * v;
  #pragma unroll
  for (int off = 32; off; off >>= 1) ss += __shfl_xor(ss, off, 64);
  __shared__ float red[6];
  if ((d & 63) == 0) red[d >> 6] = ss;
  __syncthreads();
  float tot = 0.f;
  #pragma unroll
  for (int i = 0; i < 6; ++i) tot += red[i];
  const float scale = rsqrtf(tot * (1.f / 384.f) + 1e-5f);
  xn_bf[idx] = f2bf(v * scale * w[d]);
}

// ---------------- residual add + RMSNorm; writes bf16 (layers) or fp32 (final) ----------------
__global__ __launch_bounds__(DMODEL)
void em_add_rmsnorm(const float* __restrict__ hidden, const float* __restrict__ res_in,
                    float* __restrict__ res_out, const float* __restrict__ w,
                    float* __restrict__ out, unsigned short* __restrict__ out_bf) {
  const int tok = blockIdx.x;
  const int d = threadIdx.x;
  const size_t idx = (size_t)tok * DMODEL + d;
  const float v = hidden[idx] + res_in[idx];
  if (res_out) res_out[idx] = v;
  float ss = v * v;
  #pragma unroll
  for (int off = 32; off; off >>= 1) ss += __shfl_xor(ss, off, 64);
  __shared__ float red[6];
  if ((d & 63) == 0) red[d >> 6] = ss;
  __syncthreads();
  float tot = 0.f;
  #pragma unroll
  for (int i = 0; i < 6; ++i) tot += red[i];
  const float scale = rsqrtf(tot * (1.f / 384.f) + 1e-5f);
  const float r = v * scale * w[d];
  if (out_bf) out_bf[idx] = f2bf(r);
  else out[idx] = r;
}

// ================ MFMA GEMM, bf16 A (+A2) in memory, fp32 W: C = (A+A2) @ W^T ================
#define TM 128
#define TN 64
#define LDT 40   // ushorts per LDS row (32 + 8 pad)
__global__ __launch_bounds__(256)
void em_gemm_abf(const unsigned short* __restrict__ A, const unsigned short* __restrict__ A2,
                 const float* __restrict__ W, float* __restrict__ C,
                 int M, int N, int K) {
  __shared__ unsigned short As[TM * LDT];
  __shared__ unsigned short Bs[TN * LDT];
  const int tid = threadIdx.x;
  const int bm = blockIdx.y * TM;
  const int bn = blockIdx.x * TN;
  const int wave = tid >> 6, lane = tid & 63;
  const int wm = (wave >> 1) * 64, wn = (wave & 1) * 32;
  const int mq = lane & 15, quad = lane >> 4;
  f32x4 acc[4][2] = {};
  const int ar = tid >> 1;
  const int ah = (tid & 1) * 16;
  const int br = tid >> 2;
  const int bk = (tid & 3) * 8;

  for (int kk = 0; kk < K; kk += 32) {
    {
      uint4 v0 = {0, 0, 0, 0}, v1 = {0, 0, 0, 0};
      const int row = bm + ar;
      if (row < M) {
        const uint4* pa = reinterpret_cast<const uint4*>(A + (size_t)row * K + kk + ah);
        v0 = pa[0]; v1 = pa[1];
        if (A2) {
          const uint4* pb = reinterpret_cast<const uint4*>(A2 + (size_t)row * K + kk + ah);
          v0 = addbf8(v0, pb[0]); v1 = addbf8(v1, pb[1]);
        }
      }
      uint4* dst = reinterpret_cast<uint4*>(As + ar * LDT + ah);
      dst[0] = v0; dst[1] = v1;
    }
    {
      const float* p = W + (size_t)(bn + br) * K + kk + bk;
      const float4 v0 = *reinterpret_cast<const float4*>(p);
      const float4 v1 = *reinterpret_cast<const float4*>(p + 4);
      uint4 pk;
      pk.x = f2bf2(v0.x, v0.y); pk.y = f2bf2(v0.z, v0.w);
      pk.z = f2bf2(v1.x, v1.y); pk.w = f2bf2(v1.z, v1.w);
      *reinterpret_cast<uint4*>(Bs + br * LDT + bk) = pk;
    }
    __syncthreads();
    bf16x8 bfr[2];
    #pragma unroll
    for (int j = 0; j < 2; ++j)
      bfr[j] = *reinterpret_cast<const bf16x8*>(Bs + (wn + j * 16 + mq) * LDT + quad * 8);
    #pragma unroll
    for (int i = 0; i < 4; ++i) {
      const bf16x8 afr = *reinterpret_cast<const bf16x8*>(As + (wm + i * 16 + mq) * LDT + quad * 8);
      acc[i][0] = __builtin_amdgcn_mfma_f32_16x16x32_bf16(afr, bfr[0], acc[i][0], 0, 0, 0);
      acc[i][1] = __builtin_amdgcn_mfma_f32_16x16x32_bf16(afr, bfr[1], acc[i][1], 0, 0, 0);
    }
    __syncthreads();
  }
  #pragma unroll
  for (int i = 0; i < 4; ++i) {
    const int mbase = bm + wm + i * 16 + quad * 4;
    #pragma unroll
    for (int j = 0; j < 2; ++j) {
      const int col = bn + wn + j * 16 + mq;
      #pragma unroll
      for (int p = 0; p < 4; ++p) {
        const int m = mbase + p;
        if (m < M) C[(size_t)m * N + col] = acc[i][j][p];
      }
    }
  }
}

// ===== transposed xproj GEMM, K-split x2: dblT[64, NTOKS] += xp[56, Kslice] @ u[:, Kslice]^T =====
// grid: (ceil(NTOKS/64), 2, dirs); dblT must be zeroed before launch.
__global__ __launch_bounds__(256)
void em_gemm_xpT(const unsigned short* __restrict__ ubf, const unsigned short* __restrict__ ubr,
                 const float* __restrict__ xpf, const float* __restrict__ xpr,
                 float* __restrict__ dblTf, float* __restrict__ dblTr) {
  const int dir = blockIdx.z;
  const int ks = blockIdx.y;                // K slice: 0..1
  const unsigned short* U = dir ? ubr : ubf;
  const float* W = dir ? xpr : xpf;
  float* C = dir ? dblTr : dblTf;
  __shared__ unsigned short As[64 * LDT];   // xp tile (56 real rows)
  __shared__ unsigned short Bs[64 * LDT];   // u tile (64 tokens)
  const int tid = threadIdx.x;
  const int bn = blockIdx.x * 64;           // token base
  const int wave = tid >> 6, lane = tid & 63;
  const int wm = wave * 16;
  const int mq = lane & 15, quad = lane >> 4;
  f32x4 acc[4] = {};
  const int sr = tid >> 2;
  const int sq = (tid & 3) * 8;
  const int k0 = ks * (EDIM / 2), k1 = k0 + EDIM / 2;

  for (int kk = k0; kk < k1; kk += 32) {
    {
      uint4 pk = {0, 0, 0, 0};
      if (sr < XDIM) {
        const float* p = W + (size_t)sr * EDIM + kk + sq;
        const float4 v0 = *reinterpret_cast<const float4*>(p);
        const float4 v1 = *reinterpret_cast<const float4*>(p + 4);
        pk.x = f2bf2(v0.x, v0.y); pk.y = f2bf2(v0.z, v0.w);
        pk.z = f2bf2(v1.x, v1.y); pk.w = f2bf2(v1.z, v1.w);
      }
      *reinterpret_cast<uint4*>(As + sr * LDT + sq) = pk;
    }
    {
      uint4 v = {0, 0, 0, 0};
      const int tok = bn + sr;
      if (tok < NTOKS)
        v = *reinterpret_cast<const uint4*>(U + (size_t)tok * EDIM + kk + sq);
      *reinterpret_cast<uint4*>(Bs + sr * LDT + sq) = v;
    }
    __syncthreads();
    const bf16x8 afr = *reinterpret_cast<const bf16x8*>(As + (wm + mq) * LDT + quad * 8);
    #pragma unroll
    for (int j = 0; j < 4; ++j) {
      const bf16x8 bfr = *reinterpret_cast<const bf16x8*>(Bs + (j * 16 + mq) * LDT + quad * 8);
      acc[j] = __builtin_amdgcn_mfma_f32_16x16x32_bf16(afr, bfr, acc[j], 0, 0, 0);
    }
    __syncthreads();
  }
  #pragma unroll
  for (int j = 0; j < 4; ++j) {
    const int tok = bn + j * 16 + mq;
    if (tok < NTOKS) {
      #pragma unroll
      for (int p = 0; p < 4; ++p) {
        const int m = wm + quad * 4 + p;
        atomicAdd(&C[(size_t)m * NTOKS + tok], acc[j][p]);
      }
    }
  }
}

// ---------------- dt projection (fp32, from dblT): dt = softplus(dblT[:24,tok]·dtw[e] + dtb) ---
__global__ __launch_bounds__(256)
void em_dtproj(const float* __restrict__ dblTf, const float* __restrict__ dblTr,
               const float* __restrict__ dtwf, const float* __restrict__ dtwr,
               const float* __restrict__ dtbf, const float* __restrict__ dtbr,
               float* __restrict__ dtf, float* __restrict__ dtr) {
  const int tok = blockIdx.x;
  const int dir = blockIdx.y;
  const float* dblT = dir ? dblTr : dblTf;
  const float* dtw = dir ? dtwr : dtwf;
  const float* dtb = dir ? dtbr : dtbf;
  float* dto = (dir ? dtr : dtf) + (size_t)tok * EDIM;
  __shared__ float r[RDIM];
  if (threadIdx.x < RDIM) r[threadIdx.x] = dblT[(size_t)threadIdx.x * NTOKS + tok];
  __syncthreads();
  for (int e = threadIdx.x; e < EDIM; e += 256) {
    float a = dtb[e];
    const float* dw = dtw + (size_t)e * RDIM;
    #pragma unroll
    for (int j = 0; j < RDIM; ++j) a += r[j] * dw[j];
    dto[e] = em_softplus(a);
  }
}

// ---------------- depthwise conv + SiLU; writes u as bf16 only ----------------
__global__ __launch_bounds__(256)
void em_conv_silu(const float* __restrict__ xz,
                  const float* __restrict__ cwf, const float* __restrict__ cbf,
                  const float* __restrict__ cwr, const float* __restrict__ cbr,
                  unsigned short* __restrict__ ubf, unsigned short* __restrict__ ubr, int L) {
  const int e = blockIdx.x * 256 + threadIdx.x;
  const int tok = blockIdx.y;
  const int dir = blockIdx.z;
  const int l = tok % L;
  const float* cw = dir ? cwr : cwf;
  const float* cb = dir ? cbr : cbf;
  const float w0 = cw[e * 4 + 0], w1 = cw[e * 4 + 1], w2 = cw[e * 4 + 2], w3 = cw[e * 4 + 3];
  float acc = cb[e];
  const float* base = xz + (size_t)tok * TWOE + e;
  if (dir == 0) {
    acc += base[0] * w3;
    if (l >= 1) acc += base[-(ptrdiff_t)TWOE] * w2;
    if (l >= 2) acc += base[-(ptrdiff_t)(2 * TWOE)] * w1;
    if (l >= 3) acc += base[-(ptrdiff_t)(3 * TWOE)] * w0;
  } else {
    acc += base[0] * w3;
    if (l + 1 < L) acc += base[TWOE] * w2;
    if (l + 2 < L) acc += base[2 * TWOE] * w1;
    if (l + 3 < L) acc += base[3 * TWOE] * w0;
  }
  (dir ? ubr : ubf)[(size_t)tok * EDIM + e] = f2bf(em_silu(acc));
}

// ================= chunked scan (templated chunk length) =================
template<int CL>
__global__ __launch_bounds__(256)
void em_scan_sum(const float* __restrict__ dtf, const float* __restrict__ dtr,
                 const unsigned short* __restrict__ ubf, const unsigned short* __restrict__ ubr,
                 const float* __restrict__ dblTf, const float* __restrict__ dblTr,
                 const float* __restrict__ Alogf, const float* __restrict__ Alogr,
                 float* __restrict__ Pfw, float* __restrict__ Prv,
                 float* __restrict__ Hfw, float* __restrict__ Hrv,
                 int L, int nchunks) {
  const int dir = blockIdx.z;
  const int n = blockIdx.y / nchunks;
  const int c = blockIdx.y % nchunks;
  const int tid = threadIdx.x;
  const int e = blockIdx.x * 256 + tid;
  const float* dt = dir ? dtr : dtf;
  const unsigned short* u = dir ? ubr : ubf;
  const float* dblT = dir ? dblTr : dblTf;
  const float* Alog = dir ? Alogr : Alogf;
  float* P = dir ? Prv : Pfw;
  float* H = dir ? Hrv : Hfw;
  const int p0 = c * CL;
  const int len = min(CL, L - p0);
  __shared__ float Bs[CL][SDIM];
  for (int i = tid; i < CL * SDIM; i += 256) {
    const int j = i % CL, s = i / CL;
    if (j < len) {
      const int pos = p0 + j;
      const int l = dir ? (L - 1 - pos) : pos;
      Bs[j][s] = dblT[(size_t)(RDIM + s) * NTOKS + (size_t)n * L + l];
    }
  }
  __syncthreads();
  float A[SDIM], h[SDIM], Pp[SDIM];
  #pragma unroll
  for (int s = 0; s < SDIM; ++s) {
    A[s] = -__expf(Alog[e * SDIM + s]);
    h[s] = 0.f; Pp[s] = 1.f;
  }
  for (int j = 0; j < len; ++j) {
    const int pos = p0 + j;
    const int l = dir ? (L - 1 - pos) : pos;
    const size_t tok = (size_t)n * L + l;
    const float dtv = dt[tok * EDIM + e];
    const float dtu = dtv * bf2f(u[tok * EDIM + e]);
    #pragma unroll
    for (int s = 0; s < SDIM; ++s) {
      const float a = __expf(dtv * A[s]);
      h[s] = a * h[s] + dtu * Bs[j][s];
      Pp[s] *= a;
    }
  }
  const size_t base = ((size_t)(n * nchunks + c) * EDIM + e) * SDIM;
  #pragma unroll
  for (int s = 0; s < SDIM; ++s) { P[base + s] = Pp[s]; H[base + s] = h[s]; }
}

__global__ __launch_bounds__(256)
void em_scan_combine(const float* __restrict__ Pfw, const float* __restrict__ Prv,
                     float* __restrict__ Hfw, float* __restrict__ Hrv, int nchunks) {
  const int dir = blockIdx.z;
  const int idx = blockIdx.x * 256 + threadIdx.x;
  const int n = idx / (EDIM * SDIM);
  const int r = idx % (EDIM * SDIM);
  const float* P = dir ? Prv : Pfw;
  float* H = dir ? Hrv : Hfw;
  float h = 0.f;
  for (int c = 0; c < nchunks; ++c) {
    const size_t b = (size_t)(n * nchunks + c) * (EDIM * SDIM) + r;
    const float pv = P[b];
    const float hf = H[b];
    H[b] = h;
    h = pv * h + hf;
  }
}

template<int CL>
__global__ __launch_bounds__(256)
void em_scan_out(const float* __restrict__ dtf, const float* __restrict__ dtr,
                 const unsigned short* __restrict__ ubf, const unsigned short* __restrict__ ubr,
                 const float* __restrict__ dblTf, const float* __restrict__ dblTr,
                 const float* __restrict__ xz,
                 const float* __restrict__ Alogf, const float* __restrict__ Alogr,
                 const float* __restrict__ Dpf, const float* __restrict__ Dpr,
                 const float* __restrict__ Hfw, const float* __restrict__ Hrv,
                 unsigned short* __restrict__ ybf, unsigned short* __restrict__ ybr,
                 int L, int nchunks) {
  const int dir = blockIdx.z;
  const int n = blockIdx.y / nchunks;
  const int c = blockIdx.y % nchunks;
  const int tid = threadIdx.x;
  const int e = blockIdx.x * 256 + tid;
  const float* dt = dir ? dtr : dtf;
  const unsigned short* u = dir ? ubr : ubf;
  const float* dblT = dir ? dblTr : dblTf;
  const float* Alog = dir ? Alogr : Alogf;
  const float* Dp = dir ? Dpr : Dpf;
  const float* Hin = dir ? Hrv : Hfw;
  unsigned short* y = dir ? ybr : ybf;
  const int p0 = c * CL;
  const int len = min(CL, L - p0);
  __shared__ float Bs[CL][SDIM];
  __shared__ float Cs[CL][SDIM];
  for (int i = tid; i < CL * 2 * SDIM; i += 256) {
    const int j = i % CL, v = i / CL;
    if (j < len) {
      const int pos = p0 + j;
      const int l = dir ? (L - 1 - pos) : pos;
      const float val = dblT[(size_t)(RDIM + v) * NTOKS + (size_t)n * L + l];
      if (v < SDIM) Bs[j][v] = val; else Cs[j][v - SDIM] = val;
    }
  }
  __syncthreads();
  float A[SDIM], h[SDIM];
  const size_t base = ((size_t)(n * nchunks + c) * EDIM + e) * SDIM;
  #pragma unroll
  for (int s = 0; s < SDIM; ++s) {
    A[s] = -__expf(Alog[e * SDIM + s]);
    h[s] = Hin[base + s];
  }
  const float De = Dp[e];
  for (int j = 0; j < len; ++j) {
    const int pos = p0 + j;
    const int l = dir ? (L - 1 - pos) : pos;
    const size_t tok = (size_t)n * L + l;
    const float dtv = dt[tok * EDIM + e];
    const float uv = bf2f(u[tok * EDIM + e]);
    const float dtu = dtv * uv;
    float acc = 0.f;
    #pragma unroll
    for (int s = 0; s < SDIM; ++s) {
      const float a = __expf(dtv * A[s]);
      h[s] = a * h[s] + dtu * Bs[j][s];
      acc += h[s] * Cs[j][s];
    }
    const float z = xz[tok * TWOE + EDIM + e];
    y[tok * EDIM + e] = f2bf((acc + uv * De) * em_silu(z));
  }
}

extern "C" void kernel_launch(void* const* d_in, const int* in_sizes, int n_in,
                              void* d_out, int out_size, void* d_ws, size_t ws_size,
                              hipStream_t stream) {
  const float* x         = (const float*)d_in[0];
  const float* patch_w   = (const float*)d_in[1];
  const float* patch_b   = (const float*)d_in[2];
  const float* cls_tok   = (const float*)d_in[3];
  const float* pos_emb   = (const float*)d_in[4];
  const float* normf     = (const float*)d_in[5];
  const float* sp_conv_w   = (const float*)d_in[6];
  const float* sp_conv_b   = (const float*)d_in[7];
  const float* sp_xproj    = (const float*)d_in[8];
  const float* sp_dtw      = (const float*)d_in[9];
  const float* sp_dtb      = (const float*)d_in[10];
  const float* sp_Alog     = (const float*)d_in[11];
  const float* sp_D        = (const float*)d_in[12];
  const float* sp_conv_w_r = (const float*)d_in[13];
  const float* sp_conv_b_r = (const float*)d_in[14];
  const float* sp_xproj_r  = (const float*)d_in[15];
  const float* sp_dtw_r    = (const float*)d_in[16];
  const float* sp_dtb_r    = (const float*)d_in[17];
  const float* sp_Alog_r   = (const float*)d_in[18];
  const float* sp_D_r      = (const float*)d_in[19];
  const float* tm_conv_w   = (const float*)d_in[20];
  const float* tm_conv_b   = (const float*)d_in[21];
  const float* tm_xproj    = (const float*)d_in[22];
  const float* tm_dtw      = (const float*)d_in[23];
  const float* tm_dtb      = (const float*)d_in[24];
  const float* tm_Alog     = (const float*)d_in[25];
  const float* tm_D        = (const float*)d_in[26];
  const float* sp_norm     = (const float*)d_in[27];
  const float* sp_inproj   = (const float*)d_in[28];
  const float* sp_outproj  = (const float*)d_in[29];
  const float* tm_norm     = (const float*)d_in[30];
  const float* tm_inproj   = (const float*)d_in[31];
  const float* tm_outproj  = (const float*)d_in[32];

  float* ws = (float*)d_ws;
  size_t o = 0;
  float* hidden   = ws + o; o += (size_t)NTOKS * DMODEL;
  float* residual = ws + o; o += (size_t)NTOKS * DMODEL;
  float* xz       = ws + o; o += (size_t)NTOKS * TWOE;
  float* dblT_f   = ws + o; o += (size_t)64 * NTOKS;     // contiguous with dblT_r for one memset
  float* dblT_r   = ws + o; o += (size_t)64 * NTOKS;
  float* dt_f     = ws + o; o += (size_t)NTOKS * EDIM;
  float* dt_r     = ws + o; o += (size_t)NTOKS * EDIM;
  unsigned short* xn_bf = (unsigned short*)(ws + o); o += (size_t)NTOKS * DMODEL / 2;
  unsigned short* ub_f  = (unsigned short*)(ws + o); o += (size_t)NTOKS * EDIM;      // 2 dirs
  unsigned short* ub_r  = ub_f + (size_t)NTOKS * EDIM;
  unsigned short* yb_f  = (unsigned short*)(ws + o); o += (size_t)NTOKS * EDIM;      // 2 dirs
  unsigned short* yb_r  = yb_f + (size_t)NTOKS * EDIM;
  const size_t sum_elems = (size_t)198 * EDIM * SDIM;    // max sets = 2*99 (tm) vs 16*7 (sp)
  float* scanP_f  = ws + o; o += sum_elems;
  float* scanP_r  = ws + o; o += sum_elems;
  float* scanH_f  = ws + o; o += sum_elems;
  float* scanH_r  = ws + o; o += sum_elems;

  unsigned short* im2col_bf = ub_f;            // aliases: unused until first conv
  float* patch_tmp = dt_f;                     // unused until first dtproj

  const int L_sp = 197, NC_sp = (197 + 31) / 32;    // 7  (CL=32)
  const int L_tm = 1576, NC_tm = (1576 + 15) / 16;  // 99 (CL=16)
  const int MT = (NTOKS + TM - 1) / TM;             // 25
  const int NT64 = (NTOKS + 63) / 64;               // 50

  // -------- patch embed: im2col(bf16) + MFMA GEMM + fused epilogue/norm --------
  em_im2col<<<(NPATCH * 768) / 256, 256, 0, stream>>>(x, im2col_bf);
  em_gemm_abf<<<dim3(DMODEL / TN, (NPATCH + TM - 1) / TM), 256, 0, stream>>>(
      im2col_bf, nullptr, patch_w, patch_tmp, NPATCH, DMODEL, 768);
  em_embed_norm<<<NTOKS, DMODEL, 0, stream>>>(patch_tmp, patch_b, cls_tok, pos_emb,
                                              sp_norm, residual, xn_bf);

  // -------- 12 spatial bimamba blocks: N=16 sequences of L=197, CL=32 --------
  for (int i = 0; i < NLAYER; ++i) {
    em_gemm_abf<<<dim3(TWOE / TN, MT), 256, 0, stream>>>(
        xn_bf, nullptr, sp_inproj + (size_t)i * TWOE * DMODEL, xz, NTOKS, TWOE, DMODEL);
    em_conv_silu<<<dim3(EDIM / 256, NTOKS, 2), 256, 0, stream>>>(
        xz, sp_conv_w + (size_t)i * EDIM * 4, sp_conv_b + (size_t)i * EDIM,
        sp_conv_w_r + (size_t)i * EDIM * 4, sp_conv_b_r + (size_t)i * EDIM,
        ub_f, ub_r, L_sp);
    hipMemsetAsync(dblT_f, 0, (size_t)128 * NTOKS * sizeof(float), stream);
    em_gemm_xpT<<<dim3(NT64, 2, 2), 256, 0, stream>>>(
        ub_f, ub_r, sp_xproj + (size_t)i * XDIM * EDIM, sp_xproj_r + (size_t)i * XDIM * EDIM,
        dblT_f, dblT_r);
    em_dtproj<<<dim3(NTOKS, 2), 256, 0, stream>>>(
        dblT_f, dblT_r, sp_dtw + (size_t)i * EDIM * RDIM, sp_dtw_r + (size_t)i * EDIM * RDIM,
        sp_dtb + (size_t)i * EDIM, sp_dtb_r + (size_t)i * EDIM, dt_f, dt_r);
    em_scan_sum<32><<<dim3(EDIM / 256, 16 * NC_sp, 2), 256, 0, stream>>>(
        dt_f, dt_r, ub_f, ub_r, dblT_f, dblT_r,
        sp_Alog + (size_t)i * EDIM * SDIM, sp_Alog_r + (size_t)i * EDIM * SDIM,
        scanP_f, scanP_r, scanH_f, scanH_r, L_sp, NC_sp);
    em_scan_combine<<<dim3(16 * EDIM * SDIM / 256, 1, 2), 256, 0, stream>>>(
        scanP_f, scanP_r, scanH_f, scanH_r, NC_sp);
    em_scan_out<32><<<dim3(EDIM / 256, 16 * NC_sp, 2), 256, 0, stream>>>(
        dt_f, dt_r, ub_f, ub_r, dblT_f, dblT_r, xz,
        sp_Alog + (size_t)i * EDIM * SDIM, sp_Alog_r + (size_t)i * EDIM * SDIM,
        sp_D + (size_t)i * EDIM, sp_D_r + (size_t)i * EDIM,
        scanH_f, scanH_r, yb_f, yb_r, L_sp, NC_sp);
    em_gemm_abf<<<dim3(DMODEL / TN, MT), 256, 0, stream>>>(
        yb_f, yb_r, sp_outproj + (size_t)i * DMODEL * EDIM, hidden, NTOKS, DMODEL, EDIM);
    const float* next_w = (i < NLAYER - 1) ? sp_norm + (size_t)(i + 1) * DMODEL : tm_norm;
    em_add_rmsnorm<<<NTOKS, DMODEL, 0, stream>>>(hidden, residual, residual,
                                                 next_w, nullptr, xn_bf);
  }

  // -------- 12 temporal mamba blocks: N=2 sequences of L=1576, CL=16 --------
  for (int i = 0; i < NLAYER; ++i) {
    em_gemm_abf<<<dim3(TWOE / TN, MT), 256, 0, stream>>>(
        xn_bf, nullptr, tm_inproj + (size_t)i * TWOE * DMODEL, xz, NTOKS, TWOE, DMODEL);
    em_conv_silu<<<dim3(EDIM / 256, NTOKS, 1), 256, 0, stream>>>(
        xz, tm_conv_w + (size_t)i * EDIM * 4, tm_conv_b + (size_t)i * EDIM,
        tm_conv_w + (size_t)i * EDIM * 4, tm_conv_b + (size_t)i * EDIM,
        ub_f, ub_r, L_tm);
    hipMemsetAsync(dblT_f, 0, (size_t)64 * NTOKS * sizeof(float), stream);
    em_gemm_xpT<<<dim3(NT64, 2, 1), 256, 0, stream>>>(
        ub_f, ub_r, tm_xproj + (size_t)i * XDIM * EDIM, tm_xproj + (size_t)i * XDIM * EDIM,
        dblT_f, dblT_r);
    em_dtproj<<<dim3(NTOKS, 1), 256, 0, stream>>>(
        dblT_f, dblT_r, tm_dtw + (size_t)i * EDIM * RDIM, tm_dtw + (size_t)i * EDIM * RDIM,
        tm_dtb + (size_t)i * EDIM, tm_dtb + (size_t)i * EDIM, dt_f, dt_r);
    em_scan_sum<16><<<dim3(EDIM / 256, 2 * NC_tm, 1), 256, 0, stream>>>(
        dt_f, dt_r, ub_f, ub_r, dblT_f, dblT_r,
        tm_Alog + (size_t)i * EDIM * SDIM, tm_Alog + (size_t)i * EDIM * SDIM,
        scanP_f, scanP_r, scanH_f, scanH_r, L_tm, NC_tm);
    em_scan_combine<<<dim3(2 * EDIM * SDIM / 256, 1, 1), 256, 0, stream>>>(
        scanP_f, scanP_r, scanH_f, scanH_r, NC_tm);
    em_scan_out<16><<<dim3(EDIM / 256, 2 * NC_tm, 1), 256, 0, stream>>>(
        dt_f, dt_r, ub_f, ub_r, dblT_f, dblT_r, xz,
        tm_Alog + (size_t)i * EDIM * SDIM, tm_Alog + (size_t)i * EDIM * SDIM,
        tm_D + (size_t)i * EDIM, tm_D + (size_t)i * EDIM,
        scanH_f, scanH_r, yb_f, yb_r, L_tm, NC_tm);
    em_gemm_abf<<<dim3(DMODEL / TN, MT), 256, 0, stream>>>(
        yb_f, nullptr, tm_outproj + (size_t)i * DMODEL * EDIM, hidden, NTOKS, DMODEL, EDIM);
    const bool last = (i == NLAYER - 1);
    const float* next_w = last ? normf : tm_norm + (size_t)(i + 1) * DMODEL;
    em_add_rmsnorm<<<NTOKS, DMODEL, 0, stream>>>(hidden, residual, last ? nullptr : residual,
                                                 next_w, last ? (float*)d_out : nullptr,
                                                 last ? nullptr : xn_bf);
  }
}